// Round 4
// baseline (1498.336 us; speedup 1.0000x reference)
//
#include <hip/hip_runtime.h>
#include <math.h>

#define HH 128
#define NPIX 16384
#define BB 8
#define MM 4096
#define NN 16384
#define LRELU_S 0.1f

typedef __attribute__((ext_vector_type(8))) short bf16x8;
typedef __attribute__((ext_vector_type(4))) float f32x4;

__device__ __forceinline__ float leaky_(float v){ return v >= 0.f ? v : LRELU_S*v; }
__device__ __forceinline__ float clamp01(float v){ return fminf(fmaxf(v, 0.f), 1.f); }
__device__ __forceinline__ float clamp02(float v){ return fminf(fmaxf(v, 0.f), 2.f); }
__device__ __forceinline__ unsigned short f2bf(float f){
  unsigned u = __float_as_uint(f);
  u = (u + 0x7FFFu + ((u >> 16) & 1u)) >> 16;
  return (unsigned short)u;
}
__device__ __forceinline__ float bf2f(unsigned short s){
  return __uint_as_float(((unsigned)s) << 16);
}

// ---------- prep: A f32 -> Abf[m][n] bf16 (streaming convert) ----------
__global__ __launch_bounds__(256) void k_prep(const float* __restrict__ A_,
                                              unsigned short* __restrict__ Abf){
  size_t i = ((size_t)blockIdx.x*256 + threadIdx.x)*8;
  float4 v0 = *(const float4*)&A_[i];
  float4 v1 = *(const float4*)&A_[i+4];
  unsigned short o[8] = { f2bf(v0.x), f2bf(v0.y), f2bf(v0.z), f2bf(v0.w),
                          f2bf(v1.x), f2bf(v1.y), f2bf(v1.z), f2bf(v1.w) };
  *(uint4*)&Abf[i] = *(uint4*)o;
}

// ---------- dn[b] = ||d[b,:]|| ----------
__global__ __launch_bounds__(256) void k_dn(const float* __restrict__ d, float* __restrict__ dn){
  int b = blockIdx.x, t = threadIdx.x;
  float ss = 0.f;
  for (int m=t; m<MM; m+=256){ float v = d[b*MM + m]; ss += v*v; }
  #pragma unroll
  for (int off=32; off; off>>=1) ss += __shfl_down(ss, off);
  __shared__ float red[4];
  if ((t & 63) == 0) red[t>>6] = ss;
  __syncthreads();
  if (t == 0) dn[b] = sqrtf(red[0]+red[1]+red[2]+red[3]);
}

// ---------- fused conv chain: x -> rk1 (round-2 proven version) ----------
__global__ __launch_bounds__(256) void k_conv_chain(const float* __restrict__ x,
    const float* __restrict__ wK, const float* __restrict__ w1, const float* __restrict__ b1,
    const float* __restrict__ w2, const float* __restrict__ b2,
    const float* __restrict__ w3, const float* __restrict__ b3,
    const float* __restrict__ alpha, float* __restrict__ rk){
  __shared__ float xs[24][128];
  __shared__ float bufA[2][22][128];
  __shared__ float bufB[2][18][128];
  __shared__ float wKs[18], w1s[100], w2s[100], w3s[100], bs[3][2];
  __shared__ float twoa;
  int blk = blockIdx.x;              // 128 = 8 b * 16 slabs
  int b = blk >> 4, slab = blk & 15, r0 = slab*8;
  int t = threadIdx.x;
  for (int i=t;i<18;i+=256) wKs[i]=wK[i];
  for (int i=t;i<100;i+=256){ w1s[i]=w1[i]; w2s[i]=w2[i]; w3s[i]=w3[i]; }
  if (t<2){ bs[0][t]=b1[t]; bs[1][t]=b2[t]; bs[2][t]=b3[t]; }
  if (t==0) twoa = 2.f*clamp02(alpha[0]);
  for (int idx=t; idx<24*128; idx+=256){
    int i = idx>>7, j = idx&127, ir = r0-8+i;
    xs[i][j] = ((unsigned)ir < 128u) ? x[b*NPIX + ir*HH + j] : 0.f;
  }
  __syncthreads();
  for (int c=0;c<2;++c)
    for (int idx=t; idx<22*128; idx+=256){
      int i = idx>>7, j = idx&127, ir = r0-7+i;
      float s = 0.f;
      if ((unsigned)ir < 128u){
        #pragma unroll
        for (int di=0;di<3;++di)
          #pragma unroll
          for (int dj=0;dj<3;++dj){
            int jj = j+dj-1;
            if ((unsigned)jj < 128u) s += xs[i+di][jj]*wKs[(c*3+di)*3+dj];
          }
      }
      bufA[c][i][j] = s;
    }
  __syncthreads();
  for (int o=0;o<2;++o)
    for (int idx=t; idx<18*128; idx+=256){
      int i = idx>>7, j = idx&127, ir = r0-5+i;
      float v = 0.f;
      if ((unsigned)ir < 128u){
        float s = bs[0][o];
        #pragma unroll
        for (int c=0;c<2;++c)
          #pragma unroll
          for (int di=0;di<5;++di)
            #pragma unroll
            for (int dj=0;dj<5;++dj){
              int jj = j+dj-2;
              if ((unsigned)jj < 128u) s += bufA[c][i+di][jj]*w1s[(o*2+c)*25+di*5+dj];
            }
        v = bufA[o][i+2][j] + leaky_(s);
      }
      bufB[o][i][j] = v;
    }
  __syncthreads();
  for (int o=0;o<2;++o)
    for (int idx=t; idx<14*128; idx+=256){
      int i = idx>>7, j = idx&127, ir = r0-3+i;
      float v = 0.f;
      if ((unsigned)ir < 128u){
        float s = bs[1][o];
        #pragma unroll
        for (int c=0;c<2;++c)
          #pragma unroll
          for (int di=0;di<5;++di)
            #pragma unroll
            for (int dj=0;dj<5;++dj){
              int jj = j+dj-2;
              if ((unsigned)jj < 128u) s += bufB[c][i+di][jj]*w2s[(o*2+c)*25+di*5+dj];
            }
        v = bufB[o][i+2][j] + leaky_(s);
      }
      bufA[o][i][j] = v;
    }
  __syncthreads();
  for (int o=0;o<2;++o)
    for (int idx=t; idx<10*128; idx+=256){
      int i = idx>>7, j = idx&127, ir = r0-1+i;
      float v = 0.f;
      if ((unsigned)ir < 128u){
        float s = bs[2][o];
        #pragma unroll
        for (int c=0;c<2;++c)
          #pragma unroll
          for (int di=0;di<5;++di)
            #pragma unroll
            for (int dj=0;dj<5;++dj){
              int jj = j+dj-2;
              if ((unsigned)jj < 128u) s += bufA[c][i+di][jj]*w3s[(o*2+c)*25+di*5+dj];
            }
        v = bufA[o][i+2][j] + leaky_(s);
      }
      bufB[o][i][j] = v;
    }
  __syncthreads();
  for (int c=0;c<2;++c)
    for (int idx=t; idx<10*128; idx+=256){
      int i = idx>>7, j = idx&127, ir = r0-1+i;
      float v = 0.f;
      if ((unsigned)ir < 128u){
        float kx = 0.f;
        #pragma unroll
        for (int di=0;di<3;++di)
          #pragma unroll
          for (int dj=0;dj<3;++dj){
            int jj = j+dj-1;
            if ((unsigned)jj < 128u) kx += xs[i+6+di][jj]*wKs[(c*3+di)*3+dj];
          }
        v = twoa*(kx - bufB[c][i][j]);
      }
      bufA[c][i][j] = v;
    }
  __syncthreads();
  for (int idx=t; idx<8*128; idx+=256){
    int i = idx>>7, j = idx&127, ir = r0+i;
    float s = 0.f;
    #pragma unroll
    for (int c=0;c<2;++c)
      #pragma unroll
      for (int di=0;di<3;++di)
        #pragma unroll
        for (int dj=0;dj<3;++dj){
          int jj = j+dj-1;
          if ((unsigned)jj < 128u) s += bufA[c][i+di][jj]*wKs[(c*3+(2-di))*3+(2-dj)];
        }
    rk[b*NPIX + ir*HH + j] = s;
  }
}

// ---------- gemm1 (round-2 proven): e[m][16], d2p[mt][8] ----------
__global__ __launch_bounds__(512) void k_gemm1mf(const unsigned short* __restrict__ Abf,
    const unsigned short* __restrict__ xtt, const float* __restrict__ d_,
    float* __restrict__ e_, float* __restrict__ d2p){
  int mt = blockIdx.x;                 // 256
  int w = threadIdx.x >> 6;            // k-split 0..8
  int lane = threadIdx.x & 63;
  int kg = lane >> 4, col = lane & 15;
  const unsigned short* Ap = Abf + (size_t)(mt*16 + col)*NN + w*2048 + kg*8;
  const unsigned short* Bp = xtt + ((size_t)(w*256 + kg)*16 + col)*8;
  f32x4 acc = {0.f,0.f,0.f,0.f};
  #pragma unroll 8
  for (int s=0; s<64; ++s){
    bf16x8 a = *(const bf16x8*)(Ap + s*32);
    bf16x8 b = *(const bf16x8*)(Bp + s*512);
    acc = __builtin_amdgcn_mfma_f32_16x16x32_bf16(a, b, acc, 0, 0, 0);
  }
  __shared__ float part[8][16][16];
  __shared__ float p2[16][16];
  #pragma unroll
  for (int j=0;j<4;++j) part[w][kg*4+j][col] = acc[j];
  __syncthreads();
  int t = threadIdx.x;
  if (t < 256){
    int r = t >> 4, b = t & 15;
    float s = 0.f;
    #pragma unroll
    for (int w2=0; w2<8; ++w2) s += part[w2][r][b];
    int m = mt*16 + r;
    float ee = s - ((b < 8) ? d_[b*MM + m] : 0.f);
    e_[m*16 + b] = ee;
    p2[r][b] = (b < 8) ? ee*ee : 0.f;
  }
  __syncthreads();
  if (t < 8){
    float s2 = 0.f;
    #pragma unroll
    for (int r2=0;r2<16;++r2) s2 += p2[r2][t];
    d2p[mt*8 + t] = s2;
  }
}

// ---------- gemm2 (VALU, one-copy A): up[ms][b][n] partials ----------
#define G2_MS 32
#define G2_MC 128          // MM/G2_MS
#define G2_NB 16
#define G2_NC 1024         // NN/G2_NB
__global__ __launch_bounds__(256) void k_gemm2v(const unsigned short* __restrict__ Abf,
    const float* __restrict__ e_, const float* __restrict__ d2p,
    const float* __restrict__ dn, const float* __restrict__ delta,
    const float* __restrict__ alpha, float* __restrict__ up){
  __shared__ float zs[BB][G2_MC];    // 4 KiB
  __shared__ float red[8][8];
  __shared__ float cf[8];
  int blk = blockIdx.x;              // 512
  int ms = blk >> 4, nb = blk & 15;
  int m0 = ms*G2_MC, n0 = nb*G2_NC;
  int t = threadIdx.x;
  // cf[b] from d2p (256 partials x 8)
  if (t < 64){
    int b = t & 7, part = t >> 3;
    float s = 0.f;
    for (int i=0;i<32;++i) s += d2p[(part*32+i)*8 + b];
    red[part][b] = s;
  }
  __syncthreads();
  if (t < 8){
    float s2 = 0.f;
    #pragma unroll
    for (int p=0;p<8;++p) s2 += red[p][t];
    float dist = fmaxf(sqrtf(s2), 1e-10f);
    float de = expf(delta[0]);
    float a = clamp02(alpha[0]);
    cf[t] = 2.f*a*(1.f - fminf(1.f, de*dn[t]/dist));
  }
  __syncthreads();
  // stage z[b][ml] = cf[b]*e[m0+ml][b]
  for (int i=t; i<BB*G2_MC; i+=256){
    int ml = i >> 3, b = i & 7;
    zs[b][ml] = cf[b]*e_[(m0+ml)*16 + b];
  }
  __syncthreads();
  float4 acc[BB];
  #pragma unroll
  for (int b=0;b<BB;++b){ acc[b].x=0.f; acc[b].y=0.f; acc[b].z=0.f; acc[b].w=0.f; }
  const unsigned short* Ap = Abf + (size_t)m0*NN + n0 + t*4;
  #pragma unroll 4
  for (int ml=0; ml<G2_MC; ++ml){
    uint2 araw = *(const uint2*)(Ap + (size_t)ml*NN);
    float a0 = bf2f((unsigned short)(araw.x & 0xffff));
    float a1 = bf2f((unsigned short)(araw.x >> 16));
    float a2 = bf2f((unsigned short)(araw.y & 0xffff));
    float a3 = bf2f((unsigned short)(araw.y >> 16));
    #pragma unroll
    for (int b=0;b<BB;++b){
      float s = zs[b][ml];
      acc[b].x += a0*s; acc[b].y += a1*s; acc[b].z += a2*s; acc[b].w += a3*s;
    }
  }
  #pragma unroll
  for (int b=0;b<BB;++b)
    *(float4*)&up[((size_t)ms*BB + b)*NN + n0 + t*4] = acc[b];
}

// ---------- combine: x = clip(x - beta*(rk + sum_ms up)); write xtt ----------
__global__ __launch_bounds__(256) void k_combine2(const float* __restrict__ up,
    const float* __restrict__ rk, const float* __restrict__ beta,
    float* __restrict__ x, unsigned short* __restrict__ xtt){
  int gid = blockIdx.x*256 + threadIdx.x;   // 32768 = 16 b x 2048 nb
  int b = gid >> 11, nb = gid & 2047, n0 = nb*8;
  if (b >= 8){
    uint4 z = {0,0,0,0};
    *(uint4*)&xtt[(size_t)(nb*16 + b)*8] = z;
    return;
  }
  float bta = clamp02(beta[0]);
  float acc[8];
  {
    float4 r0 = *(const float4*)&rk[b*NPIX + n0];
    float4 r1 = *(const float4*)&rk[b*NPIX + n0 + 4];
    acc[0]=r0.x; acc[1]=r0.y; acc[2]=r0.z; acc[3]=r0.w;
    acc[4]=r1.x; acc[5]=r1.y; acc[6]=r1.z; acc[7]=r1.w;
  }
  #pragma unroll 8
  for (int ms=0; ms<G2_MS; ++ms){
    const float* u = &up[((size_t)ms*BB + b)*NN + n0];
    float4 u0 = *(const float4*)u;
    float4 u1 = *(const float4*)(u+4);
    acc[0]+=u0.x; acc[1]+=u0.y; acc[2]+=u0.z; acc[3]+=u0.w;
    acc[4]+=u1.x; acc[5]+=u1.y; acc[6]+=u1.z; acc[7]+=u1.w;
  }
  float xv[8]; unsigned short o[8];
  #pragma unroll
  for (int j=0;j<8;++j){
    xv[j] = clamp01(x[b*NPIX + n0 + j] - bta*acc[j]);
    o[j] = f2bf(xv[j]);
  }
  #pragma unroll
  for (int j=0;j<8;++j) x[b*NPIX + n0 + j] = xv[j];
  *(uint4*)&xtt[(size_t)(nb*16 + b)*8] = *(uint4*)o;
}

extern "C" void kernel_launch(void* const* d_in, const int* in_sizes, int n_in,
                              void* d_out, int out_size, void* d_ws, size_t ws_size,
                              hipStream_t stream) {
  const float* d_d   = (const float*)d_in[0];
  const float* d_A   = (const float*)d_in[1];
  const float* w1    = (const float*)d_in[2];
  const float* b1    = (const float*)d_in[3];
  const float* w2    = (const float*)d_in[4];
  const float* b2    = (const float*)d_in[5];
  const float* w3    = (const float*)d_in[6];
  const float* b3    = (const float*)d_in[7];
  const float* wK    = (const float*)d_in[8];
  const float* delta = (const float*)d_in[9];
  const float* alpha = (const float*)d_in[10];
  const float* beta  = (const float*)d_in[12];

  char* p = (char*)d_ws;
  unsigned short* Abf = (unsigned short*)p; p += (size_t)MM*NN*2;      // 128 MiB
  unsigned short* xtt = (unsigned short*)p; p += (size_t)2048*16*8*2;  // 512 KiB
  float* x   = (float*)p; p += (size_t)BB*NPIX*4;
  float* rk1 = (float*)p; p += (size_t)BB*NPIX*4;
  float* e_  = (float*)p; p += (size_t)MM*16*4;                        // 256 KiB
  float* up  = (float*)p; p += (size_t)G2_MS*BB*NN*4;                  // 16 MiB
  float* d2p = (float*)p; p += (size_t)256*8*4;
  float* dnb = (float*)p; p += 64;

  k_prep<<<MM*NN/(256*8), 256, 0, stream>>>(d_A, Abf);
  k_dn<<<BB, 256, 0, stream>>>(d_d, dnb);
  hipMemsetAsync(x, 0, (size_t)BB*NPIX*4, stream);
  hipMemsetAsync(xtt, 0, (size_t)2048*16*8*2, stream);

  for (int it=0; it<9; ++it){
    k_conv_chain<<<128, 256, 0, stream>>>(x, wK, w1, b1, w2, b2, w3, b3, alpha, rk1);
    k_gemm1mf<<<256, 512, 0, stream>>>(Abf, xtt, d_d, e_, d2p);
    k_gemm2v<<<G2_MS*G2_NB, 256, 0, stream>>>(Abf, e_, d2p, dnb, delta, alpha, up);
    k_combine2<<<128, 256, 0, stream>>>(up, rk1, beta, x, xtt);
  }

  hipMemcpyAsync(d_out, x, (size_t)BB*NPIX*4, hipMemcpyDeviceToDevice, stream);
}